// Round 4
// baseline (60.324 us; speedup 1.0000x reference)
//
#include <hip/hip_runtime.h>
#include <math.h>

// Bahdanau attention, fp32. B=4, TQ=TV=256, H=D=512, U=256.
// out = [context (4*256*512)] ++ [attn (4*256*256)]
//
// tanh(x) = 1 - 2/(e^{2x}+1); e^{2(q+v)} = e^{2q}*e^{2v}.
// Pipeline: proj_partial (K-split GEMM, 256 blocks) -> proj_combine (sum+exp)
//           -> fused_attn (score 1 rcp/elem, softmax, context).
// Additive constant (sum(Vw)+bV) cancels in softmax and is dropped.

typedef float f4 __attribute__((ext_vector_type(4)));
typedef float f2 __attribute__((ext_vector_type(2)));

#define B_   4
#define TQ_  256
#define TV_  256
#define D_   512
#define U_   256
#define KDIM 512           // H == D == 512
#define MROWS 1024         // B*TQ == B*TV
#define BKP  32            // proj K-tile
#define KHALF 256          // K-split: each block does 256 of K=512

#define C2LOG2E 2.8853900817779268f   // 2*log2(e)

// ws layout (floats): Pq0 Pq1 Pv0 Pv1 (262144 each) | Eq (1048576) | Ev (1310720)
#define PELEMS 262144      // 1024*256
#define EQ_OFF 1048576
#define EV_OFF 1310720

#if __has_builtin(__builtin_amdgcn_exp2f)
#define EXP2F(x) __builtin_amdgcn_exp2f(x)
#else
#define EXP2F(x) exp2f(x)
#endif
#if __has_builtin(__builtin_amdgcn_rcpf)
#define RCPF(x) __builtin_amdgcn_rcpf(x)
#else
#define RCPF(x) (1.0f / (x))
#endif

// ---------------- K-split projection GEMM ----------------
// P[1024,256] += A[1024, khalf-slice] @ W[slice, 256]
// blockIdx.z: bit0 = proj (0: query/W1, 1: values/W2), bit1 = K-half.
// 64x64 tile, BK=32, 256 threads, 4x4 micro-tile, register-prefetch dbuf.
__global__ __launch_bounds__(256) void proj_partial(
    const float* __restrict__ query, const float* __restrict__ values,
    const float* __restrict__ W1, const float* __restrict__ W2,
    float* __restrict__ ws)
{
    const int proj = blockIdx.z & 1;
    const int kh   = blockIdx.z >> 1;
    const float* A = proj ? values : query;
    const float* W = proj ? W2 : W1;
    float* P = ws + (size_t)(proj * 2 + kh) * PELEMS;

    __shared__ __align__(16) float As[BKP][68];   // [k][m] (transposed store)
    __shared__ __align__(16) float Bs[BKP][68];   // [k][n]

    const int tid = threadIdx.x;
    const int tx = tid & 15, ty = tid >> 4;
    const int m0 = blockIdx.y * 64;
    const int n0 = blockIdx.x * 64;

    const int am = tid >> 2;          // A row 0..63
    const int ak = (tid & 3) * 8;     // A k-offset (two f4)
    const int wk = tid >> 3;          // W k-row 0..31
    const int wn = (tid & 7) * 8;     // W n-offset (two f4)

    const float* Arow = A + (size_t)(m0 + am) * KDIM + kh * KHALF + ak;
    const float* Wrow = W + (size_t)(kh * KHALF + wk) * U_ + n0 + wn;

    f4 pa0 = *(const f4*)(Arow);
    f4 pa1 = *(const f4*)(Arow + 4);
    f4 pb0 = *(const f4*)(Wrow);
    f4 pb1 = *(const f4*)(Wrow + 4);

    float acc[4][4] = {};

    const int NSTEP = KHALF / BKP;   // 8
    for (int s = 0; s < NSTEP; ++s) {
        __syncthreads();
        #pragma unroll
        for (int j = 0; j < 4; ++j) {
            As[ak + j][am]     = pa0[j];
            As[ak + 4 + j][am] = pa1[j];
        }
        *(f4*)&Bs[wk][wn]     = pb0;
        *(f4*)&Bs[wk][wn + 4] = pb1;
        __syncthreads();

        if (s + 1 < NSTEP) {
            const float* An = Arow + (size_t)(s + 1) * BKP;
            const float* Wn = Wrow + (size_t)(s + 1) * BKP * U_;
            pa0 = *(const f4*)(An);
            pa1 = *(const f4*)(An + 4);
            pb0 = *(const f4*)(Wn);
            pb1 = *(const f4*)(Wn + 4);
        }

        #pragma unroll
        for (int kk = 0; kk < BKP; ++kk) {
            f4 av = *(const f4*)&As[kk][ty * 4];
            f4 bv = *(const f4*)&Bs[kk][tx * 4];
            #pragma unroll
            for (int i = 0; i < 4; ++i)
                #pragma unroll
                for (int j = 0; j < 4; ++j)
                    acc[i][j] = fmaf(av[i], bv[j], acc[i][j]);
        }
    }

    #pragma unroll
    for (int i = 0; i < 4; ++i) {
        f4 o = {acc[i][0], acc[i][1], acc[i][2], acc[i][3]};
        *(f4*)&P[(size_t)(m0 + ty * 4 + i) * U_ + n0 + tx * 4] = o;
    }
}

// ---------------- combine: E = exp2(C * (P0 + P1 + bias)) ----------------
// 131072 f4 elements total (both projections). One f4 per thread.
__global__ __launch_bounds__(256) void proj_combine(
    const float* __restrict__ b1, const float* __restrict__ b2,
    float* __restrict__ ws)
{
    const int g = blockIdx.x * 256 + threadIdx.x;   // 0..131071
    const int proj = g >> 16;                        // 65536 f4 per projection
    const int rem  = g & 65535;
    const int n4   = rem & 63;                       // f4 column index

    const f4* wsf4 = (const f4*)ws;
    f4 p0 = wsf4[(size_t)proj * 131072 + rem];
    f4 p1 = wsf4[(size_t)proj * 131072 + 65536 + rem];
    f4 bias = ((const f4*)(proj ? b2 : b1))[n4];

    f4 e;
    #pragma unroll
    for (int j = 0; j < 4; ++j)
        e[j] = EXP2F((p0[j] + p1[j] + bias[j]) * C2LOG2E);

    ((f4*)ws)[(size_t)262144 + (size_t)proj * 65536 + rem] = e;
}

// ---------------- fused score + softmax + context ----------------
// One block = (batch b, 4 q rows). 1024 threads (16 waves).
// Score: thread t -> v = t&255, u-quarter = t>>8; partials in LDS.
// Softmax: wave w < 4 handles q-row w. Context: quarter-block per q-row.
__global__ __launch_bounds__(1024) void fused_attn(
    const float* __restrict__ values, const float* __restrict__ Vw,
    const float* __restrict__ ws, float* __restrict__ out)
{
    __shared__ __align__(16) float eq[4][U_];       // Eq rows (4 q's)
    __shared__ __align__(16) float vw[U_];
    __shared__ __align__(16) float scr[4][4][TV_];  // scr[uq][qi][v]

    const float* Eq = ws + EQ_OFF;
    const float* Ev = ws + EV_OFF;

    const int tid = threadIdx.x;
    const int b  = blockIdx.y;
    const int q0 = blockIdx.x * 4;

    ((float*)eq)[tid] = Eq[(size_t)(b * TQ_ + q0) * U_ + tid];  // 4 contiguous rows
    if (tid < U_) vw[tid] = Vw[tid];
    __syncthreads();

    const int v  = tid & 255;
    const int uq = tid >> 8;          // u-quarter: [uq*64, uq*64+64)
    const int u0 = uq * 64;

    // ---- scores: p = sum_u Vw[u] / (Eq[q,u]*Ev[v,u] + 1)  (score = const - 2p)
    {
        const f4* evp = (const f4*)&Ev[((size_t)(b * TV_ + v)) * U_ + u0];
        const f4* q40 = (const f4*)&eq[0][u0];
        const f4* q41 = (const f4*)&eq[1][u0];
        const f4* q42 = (const f4*)&eq[2][u0];
        const f4* q43 = (const f4*)&eq[3][u0];
        const f4* vwp = (const f4*)&vw[u0];

        float sc0 = 0.f, sc1 = 0.f, sc2 = 0.f, sc3 = 0.f;
        #pragma unroll 4
        for (int i = 0; i < 16; ++i) {
            f4 ev4 = evp[i];
            f4 w4  = vwp[i];
            f4 a0 = q40[i], a1 = q41[i], a2 = q42[i], a3 = q43[i];
            #pragma unroll
            for (int j = 0; j < 4; ++j) {
                float e, r;
                e = a0[j] * ev4[j]; r = RCPF(e + 1.f); sc0 = fmaf(w4[j], r, sc0);
                e = a1[j] * ev4[j]; r = RCPF(e + 1.f); sc1 = fmaf(w4[j], r, sc1);
                e = a2[j] * ev4[j]; r = RCPF(e + 1.f); sc2 = fmaf(w4[j], r, sc2);
                e = a3[j] * ev4[j]; r = RCPF(e + 1.f); sc3 = fmaf(w4[j], r, sc3);
            }
        }
        scr[uq][0][v] = sc0;
        scr[uq][1][v] = sc1;
        scr[uq][2][v] = sc2;
        scr[uq][3][v] = sc3;
    }
    __syncthreads();

    // ---- softmax over v: wave w in [0,4) handles q-row w
    {
        const int w = tid >> 6, lane = tid & 63;
        if (w < 4) {
            float p0 = scr[0][w][lane]       + scr[1][w][lane]
                     + scr[2][w][lane]       + scr[3][w][lane];
            float p1 = scr[0][w][lane + 64]  + scr[1][w][lane + 64]
                     + scr[2][w][lane + 64]  + scr[3][w][lane + 64];
            float p2 = scr[0][w][lane + 128] + scr[1][w][lane + 128]
                     + scr[2][w][lane + 128] + scr[3][w][lane + 128];
            float p3 = scr[0][w][lane + 192] + scr[1][w][lane + 192]
                     + scr[2][w][lane + 192] + scr[3][w][lane + 192];
            float m = fminf(fminf(p0, p1), fminf(p2, p3));  // max score = min p
            #pragma unroll
            for (int off = 32; off; off >>= 1) m = fminf(m, __shfl_xor(m, off));
            float e0 = EXP2F((m - p0) * C2LOG2E);
            float e1 = EXP2F((m - p1) * C2LOG2E);
            float e2 = EXP2F((m - p2) * C2LOG2E);
            float e3 = EXP2F((m - p3) * C2LOG2E);
            float sum = e0 + e1 + e2 + e3;
            #pragma unroll
            for (int off = 32; off; off >>= 1) sum += __shfl_xor(sum, off);
            const float rinv = 1.0f / sum;    // exact division
            e0 *= rinv; e1 *= rinv; e2 *= rinv; e3 *= rinv;
            scr[0][w][lane]       = e0;
            scr[0][w][lane + 64]  = e1;
            scr[0][w][lane + 128] = e2;
            scr[0][w][lane + 192] = e3;
            float* attn_out = out + (size_t)B_ * TQ_ * D_;
            const size_t rb = ((size_t)(b * TQ_ + q0 + w)) * TV_;
            attn_out[rb + lane]       = e0;
            attn_out[rb + lane + 64]  = e1;
            attn_out[rb + lane + 128] = e2;
            attn_out[rb + lane + 192] = e3;
        }
    }
    __syncthreads();

    // ---- context: quarter-block qh owns q-row qh; thread owns d = {2*d2, 2*d2+1}
    {
        const int qh = tid >> 8;
        const int d2 = tid & 255;
        f2 acc = {0.f, 0.f};
        const f2* vals2 = (const f2*)&values[(size_t)b * TV_ * D_];
        #pragma unroll 4
        for (int vv = 0; vv < TV_; ++vv) {
            f2 val = vals2[(size_t)vv * (D_ / 2) + d2];
            acc += scr[0][qh][vv] * val;
        }
        *(f2*)&out[((size_t)(b * TQ_ + q0 + qh)) * D_ + 2 * d2] = acc;
    }
}

extern "C" void kernel_launch(void* const* d_in, const int* in_sizes, int n_in,
                              void* d_out, int out_size, void* d_ws, size_t ws_size,
                              hipStream_t stream) {
    const float* query  = (const float*)d_in[0];
    const float* values = (const float*)d_in[1];
    const float* W1     = (const float*)d_in[2];
    const float* b1     = (const float*)d_in[3];
    const float* W2     = (const float*)d_in[4];
    const float* b2     = (const float*)d_in[5];
    const float* Vw     = (const float*)d_in[6];
    float* out = (float*)d_out;
    float* ws  = (float*)d_ws;

    proj_partial<<<dim3(U_ / 64, MROWS / 64, 4), 256, 0, stream>>>(
        query, values, W1, W2, ws);
    proj_combine<<<512, 256, 0, stream>>>(b1, b2, ws);
    fused_attn<<<dim3(TQ_ / 4, B_), 1024, 0, stream>>>(
        values, Vw, ws, out);
}

// Round 5
// 58.303 us; speedup vs baseline: 1.0347x; 1.0347x over previous
//
#include <hip/hip_runtime.h>
#include <math.h>

// Bahdanau attention, fp32. B=4, TQ=TV=256, H=D=512, U=256.
// out = [context (4*256*512)] ++ [attn (4*256*256)]
//
// tanh(x) = 1 - 2/(e^{2x}+1); e^{2(q+v)} = e^{2q}*e^{2v}.
// proj_partial: K-split GEMMs -> Pq[q][u] partials and PvT[u][vg] partials
//   (V-projection computed TRANSPOSED so the fused score loop reads EvT
//    lane-consecutive in v: coalesced. Round-4's Ev[v][u] layout made every
//    lane read a different 1KB-strided row -> L1 serialization, 45us.)
// proj_combine: E = exp2(C*(sum partials + bias)) for Eq and EvT.
// fused_attn: score (1 rcp + 2 fma per element), softmax, context.
// Additive constant (sum(Vw)+bV) cancels in softmax and is dropped.

typedef float f4 __attribute__((ext_vector_type(4)));
typedef float f2 __attribute__((ext_vector_type(2)));

#define B_    4
#define TQ_   256
#define TV_   256
#define D_    512
#define U_    256
#define KDIM  512          // H == D == 512
#define MROWS 1024         // B*TQ == B*TV
#define BKP   32           // proj LDS K-tile
#define KQ    128          // proj K-split quarter
#define NSTEP (KQ / BKP)   // 4

#define C2LOG2E 2.8853900817779268f   // 2*log2(e)

// ws layout (f4 units of 65536 per 1024x256 buffer):
//   [0..3]  Pq partials   [q-row][u]     (4 K-quarters)
//   [4..7]  PvT partials  [u][vglobal]   (4 K-quarters)
//   [8]     Eq  = exp2(C*(Qp))  [q-row][u]
//   [9]     EvT = exp2(C*(Vp))  [u][vglobal]
#define PELEMS  262144
#define EQ_OFF  (8 * PELEMS)
#define EVT_OFF (9 * PELEMS)

#if __has_builtin(__builtin_amdgcn_exp2f)
#define EXP2F(x) __builtin_amdgcn_exp2f(x)
#else
#define EXP2F(x) exp2f(x)
#endif
#if __has_builtin(__builtin_amdgcn_rcpf)
#define RCPF(x) __builtin_amdgcn_rcpf(x)
#else
#define RCPF(x) (1.0f / (x))
#endif

// ---------------- K-split projection GEMMs ----------------
// proj 0: Pq[m=1024 q-rows][n=256 u]   = query[m][k] @ W1[k][n]
// proj 1: PvT[m=256 u][n=1024 vglobal] = W2[k][m]^T-as-A @ values[n][k]^T-as-B
// Both: 64x64 tile, BK=32, 256 threads, 4x4 micro-tile, reg-prefetch dbuf.
// T-path stages a [row][k] source transposed into LDS [k][row];
// D-path stages a [k][col] source directly. The two projs swap which of
// As/Bs gets which path.
__global__ __launch_bounds__(256) void proj_partial(
    const float* __restrict__ query, const float* __restrict__ values,
    const float* __restrict__ W1, const float* __restrict__ W2,
    float* __restrict__ ws)
{
    const int proj = blockIdx.z;    // 0: Pq, 1: PvT
    const int ks   = blockIdx.y;    // K-quarter
    const int tile = blockIdx.x;    // 0..63

    __shared__ __align__(16) float As[BKP][68];
    __shared__ __align__(16) float Bs[BKP][68];

    const int tid = threadIdx.x;
    const int tx = tid & 15, ty = tid >> 4;
    const int trow = tid >> 2, tk = (tid & 3) * 8;   // T-path: 64 rows x 8 k
    const int dk = tid >> 3, dcol = (tid & 7) * 8;   // D-path: 32 k x 64 cols
    const int kb = ks * KQ;

    int m0, n0;
    const float* Tsrc;
    const float* Dsrc;
    if (proj == 0) {
        m0 = (tile >> 2) * 64;  n0 = (tile & 3) * 64;
        Tsrc = query  + (size_t)(m0 + trow) * KDIM + kb + tk;  // -> As[k][m]
        Dsrc = W1     + (size_t)(kb + dk) * U_ + n0 + dcol;    // -> Bs[k][n]
    } else {
        m0 = (tile & 3) * 64;   n0 = (tile >> 2) * 64;
        Tsrc = values + (size_t)(n0 + trow) * KDIM + kb + tk;  // -> Bs[k][n]
        Dsrc = W2     + (size_t)(kb + dk) * U_ + m0 + dcol;    // -> As[k][m]
    }

    f4 t0 = *(const f4*)(Tsrc);
    f4 t1 = *(const f4*)(Tsrc + 4);
    f4 d0 = *(const f4*)(Dsrc);
    f4 d1 = *(const f4*)(Dsrc + 4);

    float acc[4][4] = {};

    for (int s = 0; s < NSTEP; ++s) {
        __syncthreads();
        if (proj == 0) {
            #pragma unroll
            for (int j = 0; j < 4; ++j) {
                As[tk + j][trow]     = t0[j];
                As[tk + 4 + j][trow] = t1[j];
            }
            *(f4*)&Bs[dk][dcol]     = d0;
            *(f4*)&Bs[dk][dcol + 4] = d1;
        } else {
            #pragma unroll
            for (int j = 0; j < 4; ++j) {
                Bs[tk + j][trow]     = t0[j];
                Bs[tk + 4 + j][trow] = t1[j];
            }
            *(f4*)&As[dk][dcol]     = d0;
            *(f4*)&As[dk][dcol + 4] = d1;
        }
        __syncthreads();

        if (s + 1 < NSTEP) {   // prefetch next K-tile into regs
            const float* Tn = Tsrc + (s + 1) * BKP;             // +k along row
            const float* Dn = Dsrc + (size_t)(s + 1) * BKP * U_; // +k rows
            t0 = *(const f4*)(Tn);
            t1 = *(const f4*)(Tn + 4);
            d0 = *(const f4*)(Dn);
            d1 = *(const f4*)(Dn + 4);
        }

        #pragma unroll
        for (int kk = 0; kk < BKP; ++kk) {
            f4 av = *(const f4*)&As[kk][ty * 4];
            f4 bv = *(const f4*)&Bs[kk][tx * 4];
            #pragma unroll
            for (int i = 0; i < 4; ++i)
                #pragma unroll
                for (int j = 0; j < 4; ++j)
                    acc[i][j] = fmaf(av[i], bv[j], acc[i][j]);
        }
    }

    const int cstride = proj ? MROWS : U_;
    float* P = ws + (size_t)(proj * 4 + ks) * PELEMS;
    #pragma unroll
    for (int i = 0; i < 4; ++i) {
        f4 o = {acc[i][0], acc[i][1], acc[i][2], acc[i][3]};
        *(f4*)&P[(size_t)(m0 + ty * 4 + i) * cstride + n0 + tx * 4] = o;
    }
}

// ---------------- combine: E = exp2(C * (sum of 4 partials + bias)) ----------
// 131072 f4 elements (Eq then EvT). Eq bias indexed by column (u);
// EvT bias indexed by row (u), wave-uniform.
__global__ __launch_bounds__(256) void proj_combine(
    const float* __restrict__ b1, const float* __restrict__ b2,
    float* __restrict__ ws)
{
    const int g = blockIdx.x * 256 + threadIdx.x;   // 0..131071
    const int proj = g >> 16;
    const int rem  = g & 65535;
    f4* wsf4 = (f4*)ws;

    f4 p = wsf4[(size_t)(proj * 4)     * 65536 + rem];
    p   += wsf4[(size_t)(proj * 4 + 1) * 65536 + rem];
    p   += wsf4[(size_t)(proj * 4 + 2) * 65536 + rem];
    p   += wsf4[(size_t)(proj * 4 + 3) * 65536 + rem];

    f4 bias;
    if (proj == 0) {
        bias = ((const f4*)b1)[rem & 63];           // u = column
    } else {
        float bb = b2[rem >> 8];                    // u = row (256 f4/row)
        bias = f4{bb, bb, bb, bb};
    }

    f4 e;
    #pragma unroll
    for (int j = 0; j < 4; ++j)
        e[j] = EXP2F((p[j] + bias[j]) * C2LOG2E);

    wsf4[(size_t)(8 + proj) * 65536 + rem] = e;
}

// ---------------- fused score + softmax + context ----------------
// One block = (batch b, 4 q rows). 1024 threads (16 waves), LDS 37KB
// -> 2 blocks/CU, phases of different blocks overlap.
// Score: thread t -> v-pair (tid&127), u-slice (tid>>7, 32 u's). EvT read is
// lane-consecutive (coalesced f2); eq/vw are LDS broadcasts.
// Softmax: wave w < 4 handles q-row w (sums 8 slice-partials).
// Context: quarter-block per q-row, thread owns d-pair; coalesced.
__global__ __launch_bounds__(1024) void fused_attn(
    const float* __restrict__ values, const float* __restrict__ Vw,
    const float* __restrict__ ws, float* __restrict__ out)
{
    __shared__ __align__(16) f4    eqT[U_];          // {eq[q0+0..3]}[u]
    __shared__ __align__(16) float vw[U_];
    __shared__ __align__(16) float scr[8][4][TV_];   // [u-slice][q][v]

    const float* Eq  = ws + EQ_OFF;
    const float* EvT = ws + EVT_OFF;

    const int tid = threadIdx.x;
    const int b  = blockIdx.y;
    const int q0 = blockIdx.x * 4;

    if (tid < U_) {
        const int u = tid;
        const size_t base = (size_t)(b * TQ_ + q0) * U_ + u;   // 4 coalesced rows
        f4 e = {Eq[base], Eq[base + U_], Eq[base + 2 * U_], Eq[base + 3 * U_]};
        eqT[u] = e;
        vw[u]  = Vw[u];
    }
    __syncthreads();

    // ---- scores: p(q,v) = sum_u vw[u] * rcp(eq[q,u]*ev[v,u] + 1)
    {
        const int v2 = tid & 127;        // owns v = {2*v2, 2*v2+1}
        const int us = tid >> 7;         // u-slice 0..7 (32 u each)
        const f2* evbase = (const f2*)(EvT + (size_t)b * TV_) + v2;

        f2 acc[4] = {{0.f, 0.f}, {0.f, 0.f}, {0.f, 0.f}, {0.f, 0.f}};
        #pragma unroll 4
        for (int i = 0; i < 32; ++i) {
            const int u = us * 32 + i;
            f2 ev = evbase[(size_t)u * (MROWS / 2)];   // coalesced, L2
            f4 eq = eqT[u];                            // broadcast
            float w = vw[u];                           // broadcast
            #pragma unroll
            for (int q = 0; q < 4; ++q) {
                float den0 = fmaf(eq[q], ev.x, 1.0f);
                float den1 = fmaf(eq[q], ev.y, 1.0f);
                acc[q].x = fmaf(w, RCPF(den0), acc[q].x);
                acc[q].y = fmaf(w, RCPF(den1), acc[q].y);
            }
        }
        #pragma unroll
        for (int q = 0; q < 4; ++q)
            *(f2*)&scr[us][q][2 * v2] = acc[q];
    }
    __syncthreads();

    // ---- softmax over v: wave w in [0,4) handles q-row w
    {
        const int w = tid >> 6, lane = tid & 63;
        if (w < 4) {
            float p0 = 0.f, p1 = 0.f, p2 = 0.f, p3 = 0.f;
            #pragma unroll
            for (int s = 0; s < 8; ++s) {
                p0 += scr[s][w][lane];
                p1 += scr[s][w][lane + 64];
                p2 += scr[s][w][lane + 128];
                p3 += scr[s][w][lane + 192];
            }
            float m = fminf(fminf(p0, p1), fminf(p2, p3));  // max score = min p
            #pragma unroll
            for (int off = 32; off; off >>= 1) m = fminf(m, __shfl_xor(m, off));
            float e0 = EXP2F((m - p0) * C2LOG2E);
            float e1 = EXP2F((m - p1) * C2LOG2E);
            float e2 = EXP2F((m - p2) * C2LOG2E);
            float e3 = EXP2F((m - p3) * C2LOG2E);
            float sum = e0 + e1 + e2 + e3;
            #pragma unroll
            for (int off = 32; off; off >>= 1) sum += __shfl_xor(sum, off);
            const float rinv = 1.0f / sum;    // exact division
            e0 *= rinv; e1 *= rinv; e2 *= rinv; e3 *= rinv;
            scr[0][w][lane]       = e0;
            scr[0][w][lane + 64]  = e1;
            scr[0][w][lane + 128] = e2;
            scr[0][w][lane + 192] = e3;
            float* attn_out = out + (size_t)B_ * TQ_ * D_;
            const size_t rb = ((size_t)(b * TQ_ + q0 + w)) * TV_;
            attn_out[rb + lane]       = e0;
            attn_out[rb + lane + 64]  = e1;
            attn_out[rb + lane + 128] = e2;
            attn_out[rb + lane + 192] = e3;
        }
    }
    __syncthreads();

    // ---- context: quarter-block qh owns q-row qh; thread owns d-pair
    {
        const int qh = tid >> 8;
        const int d2 = tid & 255;
        f2 acc = {0.f, 0.f};
        const f2* vals2 = (const f2*)&values[(size_t)b * TV_ * D_];
        #pragma unroll 4
        for (int vv = 0; vv < TV_; ++vv) {
            f2 val = vals2[(size_t)vv * (D_ / 2) + d2];
            acc += scr[0][qh][vv] * val;
        }
        *(f2*)&out[((size_t)(b * TQ_ + q0 + qh)) * D_ + 2 * d2] = acc;
    }
}

extern "C" void kernel_launch(void* const* d_in, const int* in_sizes, int n_in,
                              void* d_out, int out_size, void* d_ws, size_t ws_size,
                              hipStream_t stream) {
    const float* query  = (const float*)d_in[0];
    const float* values = (const float*)d_in[1];
    const float* W1     = (const float*)d_in[2];
    const float* b1     = (const float*)d_in[3];
    const float* W2     = (const float*)d_in[4];
    const float* b2     = (const float*)d_in[5];
    const float* Vw     = (const float*)d_in[6];
    float* out = (float*)d_out;
    float* ws  = (float*)d_ws;

    proj_partial<<<dim3(64, 4, 2), 256, 0, stream>>>(query, values, W1, W2, ws);
    proj_combine<<<dim3(512), 256, 0, stream>>>(b1, b2, ws);
    fused_attn<<<dim3(TQ_ / 4, B_), 1024, 0, stream>>>(values, Vw, ws, out);
}